// Round 1
// 679.914 us; speedup vs baseline: 1.1079x; 1.1079x over previous
//
#include <hip/hip_runtime.h>
#include <hip/hip_bf16.h>
#include <stdint.h>

typedef __bf16 bf16_t;
typedef __bf16 bf16x8 __attribute__((ext_vector_type(8)));
typedef __bf16 bf16x4_t __attribute__((ext_vector_type(4)));
typedef float f32x4 __attribute__((ext_vector_type(4)));

#define AS1 __attribute__((address_space(1)))
#define AS3 __attribute__((address_space(3)))

__device__ __forceinline__ void stage16(const bf16_t* g, char* l) {
    __builtin_amdgcn_global_load_lds((const AS1 uint32_t*)g, (AS3 uint32_t*)l, 16, 0, 0);
}

#define BAR()   __builtin_amdgcn_s_barrier()
#define LGKM0() asm volatile("s_waitcnt lgkmcnt(0)" ::: "memory")
#define VMC(N)  asm volatile("s_waitcnt vmcnt(" #N ")" ::: "memory")
#define PRIO(p) __builtin_amdgcn_s_setprio(p)

// ----------------------------------------------------------------------------
// 256x256 8-phase bf16 GEMM (m201-style template): C = A * Bt^T + bias.
// 512 threads = 8 waves (2M x 4N); per-wave output 128x64; BK=128 per loop iter
// split as 2 K-tiles of 64 across 2 LDS buffers; each K-tile staged as 4
// half-tiles [256 rows][32 k] (A-k0, B-k0, A-k1, B-k1), 16 KB each -> 128 KB LDS.
// st_16x32 LDS swizzle: within each [16r][32c] 1KB subtile, col ^= 16 when row&8.
// Applied as inverse-swizzle on the global SOURCE address (global_load_lds dest
// is linear) + the same XOR on the ds_read address (rule #21, both-sides).
// Schedule per iteration (phases P1..P8); every phase stages the region freed
// by the previous phase; counted vmcnt(6) only at P4/P8 (3 half-tiles in flight):
//   P1: rd A(b0,k0)+B(b0,k0,nh0) | stg B(b1,k1)@prev  | mfma nh0
//   P2: rd B(b0,k0,nh1)          | stg A(b0,k0)@next0 | mfma nh1
//   P3: rd A(b0,k1)+B(b0,k1,nh0) | stg B(b0,k0)@next0 | mfma nh0
//   P4: rd B(b0,k1,nh1)          | stg A(b0,k1)@next0 | mfma nh1 | vmcnt(6)
//   P5..P8: same on buf1 with next1.
// ----------------------------------------------------------------------------
template <typename OutT>
__global__ __launch_bounds__(512, 2) void gemm256(
    const bf16_t* __restrict__ A, int lda,
    const bf16_t* __restrict__ Bt, int ldb,
    const float* __restrict__ bias,
    OutT* __restrict__ C, int ldc,
    int K, int nTilesN)
{
    __shared__ char smem[131072];
    const int tid  = threadIdx.x;
    const int wave = tid >> 6;
    const int lane = tid & 63;
    const int wm = wave >> 2;   // 0..1 -> rows wm*128..+128
    const int wn = wave & 3;    // 0..3 -> cols wn*64..+64

    // XCD-aware bijective swizzle (gridDim.x % 8 == 0 guaranteed by caller)
    const int bid = blockIdx.x;
    const int swz = (bid & 7) * ((int)gridDim.x >> 3) + (bid >> 3);
    const int m0 = (swz / nTilesN) << 8;
    const int n0 = (swz % nTilesN) << 8;

    // Staging source: wave w, inst j covers subtile rg=w*2+j (rows rg*16+srow of
    // the 256-row half-tile); lane's 16B chunk col = (lane&3)*8, XOR 16 when the
    // subtile row (lane>>2) has bit 3 set (inverse st_16x32 pre-swizzle).
    const int srow = lane >> 2;
    const int scol = ((lane & 3) * 8) ^ ((lane & 32) >> 1);
    const bf16_t* aS0 = A  + (size_t)(m0 + wave * 32 + srow) * lda + scol;
    const bf16_t* aS1 = aS0 + (size_t)16 * lda;
    const bf16_t* bS0 = Bt + (size_t)(n0 + wave * 32 + srow) * ldb + scol;
    const bf16_t* bS1 = bS0 + (size_t)16 * ldb;

    // LDS map: A(b,kk) = b*65536 + kk*16384 ; B(b,kk) = +32768.
#define STAGE_A(b,kk,kb) do { \
    stage16(aS0 + (kb) + (kk)*32, smem + (b)*65536 + (kk)*16384 + wave*2048); \
    stage16(aS1 + (kb) + (kk)*32, smem + (b)*65536 + (kk)*16384 + wave*2048 + 1024); } while(0)
#define STAGE_B(b,kk,kb) do { \
    stage16(bS0 + (kb) + (kk)*32, smem + (b)*65536 + 32768 + (kk)*16384 + wave*2048); \
    stage16(bS1 + (kb) + (kk)*32, smem + (b)*65536 + 32768 + (kk)*16384 + wave*2048 + 1024); } while(0)

    // ds_read: lane l -> row l&15 of row-group, k-chunk (l>>4)*8 bf16, with the
    // st_16x32 XOR (row bit 3 <-> col-byte bit 5).
    const int rdLane = (lane & 15) * 64 + (((lane >> 4) * 16) ^ ((lane & 8) << 2));
    const char* aRdB = smem + rdLane + wm * 8192;           // + mi*1024 + A(b,kk)
    const char* bRdB = smem + 32768 + rdLane + wn * 4096;   // + ni*1024 + base(b,kk)

    f32x4 acc[8][4];
#pragma unroll
    for (int i = 0; i < 8; ++i)
#pragma unroll
        for (int j = 0; j < 4; ++j) acc[i][j] = (f32x4){0.f, 0.f, 0.f, 0.f};
    bf16x8 a[8], bf0, bf1;

#define READ_A(b,kk) { _Pragma("unroll") \
    for (int mi = 0; mi < 8; ++mi) \
        a[mi] = *(const bf16x8*)(aRdB + (b)*65536 + (kk)*16384 + mi*1024); }
#define READ_B(b,kk,nh) { \
    bf0 = *(const bf16x8*)(bRdB + (b)*65536 + (kk)*16384 + (nh)*2048); \
    bf1 = *(const bf16x8*)(bRdB + (b)*65536 + (kk)*16384 + (nh)*2048 + 1024); }
#define MFMA_H(nh) { _Pragma("unroll") \
    for (int mi = 0; mi < 8; ++mi) { \
        acc[mi][(nh)*2]   = __builtin_amdgcn_mfma_f32_16x16x32_bf16(a[mi], bf0, acc[mi][(nh)*2],   0, 0, 0); \
        acc[mi][(nh)*2+1] = __builtin_amdgcn_mfma_f32_16x16x32_bf16(a[mi], bf1, acc[mi][(nh)*2+1], 0, 0, 0); } }
#define PHASE(RDS, STG, MF, WAIT) do { \
    RDS; STG; BAR(); LGKM0(); PRIO(1); MF; PRIO(0); WAIT; BAR(); } while(0)

    // Prologue: 7 half-tiles (buf0 tile0 complete, buf1 tile1 minus B-k1);
    // vmcnt(6) -> buf0's 4 half-tiles (8 oldest loads) landed.
    STAGE_A(0, 0, 0);  STAGE_B(0, 0, 0);  STAGE_A(0, 1, 0);  STAGE_B(0, 1, 0);
    STAGE_A(1, 0, 64); STAGE_B(1, 0, 64); STAGE_A(1, 1, 64);
    VMC(6);
    BAR();

    const int NI = K >> 7;
    for (int it = 0; it < NI - 1; ++it) {
        const int kB  = (it << 7) + 64;    // buf1 tile (this iter), B-k1 leftover
        const int kN0 = (it << 7) + 128;   // next buf0 tile
        const int kN1 = (it << 7) + 192;   // next buf1 tile
        PHASE(READ_A(0,0); READ_B(0,0,0), STAGE_B(1,1,kB),  MFMA_H(0), );
        PHASE(READ_B(0,0,1),              STAGE_A(0,0,kN0), MFMA_H(1), );
        PHASE(READ_A(0,1); READ_B(0,1,0), STAGE_B(0,0,kN0), MFMA_H(0), );
        PHASE(READ_B(0,1,1),              STAGE_A(0,1,kN0), MFMA_H(1), VMC(6));
        PHASE(READ_A(1,0); READ_B(1,0,0), STAGE_B(0,1,kN0), MFMA_H(0), );
        PHASE(READ_B(1,0,1),              STAGE_A(1,0,kN1), MFMA_H(1), );
        PHASE(READ_A(1,1); READ_B(1,1,0), STAGE_B(1,0,kN1), MFMA_H(0), );
        PHASE(READ_B(1,1,1),              STAGE_A(1,1,kN1), MFMA_H(1), VMC(6));
    }
    // Epilogue: last two K-tiles; only the buf1 B-k1 leftover still needs staging.
    {
        const int kB = ((NI - 1) << 7) + 64;
        PHASE(READ_A(0,0); READ_B(0,0,0), STAGE_B(1,1,kB), MFMA_H(0), );
        PHASE(READ_B(0,0,1),             ,                 MFMA_H(1), );
        PHASE(READ_A(0,1); READ_B(0,1,0),,                 MFMA_H(0), );
        PHASE(READ_B(0,1,1),             ,                 MFMA_H(1), VMC(0));
        PHASE(READ_A(1,0); READ_B(1,0,0),,                 MFMA_H(0), );
        PHASE(READ_B(1,0,1),             ,                 MFMA_H(1), );
        PHASE(READ_A(1,1); READ_B(1,1,0),,                 MFMA_H(0), );
        READ_B(1,1,1); BAR(); LGKM0(); PRIO(1); MFMA_H(1); PRIO(0);
    }

    // D layout: col = lane&15, row = quad*4 + reg (m89-verified convention).
    const int mrow = lane & 15;
    const int quad = lane >> 4;
    const int cb = n0 + wn * 64 + mrow;
    const int rb = m0 + wm * 128 + quad * 4;
#pragma unroll
    for (int ni = 0; ni < 4; ++ni) {
        const int col = cb + ni * 16;
        const float bv = bias[col];
#pragma unroll
        for (int mi = 0; mi < 8; ++mi) {
            const int row = rb + mi * 16;
#pragma unroll
            for (int r = 0; r < 4; ++r)
                C[(size_t)(row + r) * ldc + col] = (OutT)(acc[mi][ni][r] + bv);
        }
    }
#undef STAGE_A
#undef STAGE_B
#undef READ_A
#undef READ_B
#undef MFMA_H
#undef PHASE
}

// fp32 -> bf16 elementwise, 4 elems/thread.
__global__ __launch_bounds__(256) void f32_to_bf16(const float* __restrict__ src,
                                                   bf16_t* __restrict__ dst, int n4) {
    int i = blockIdx.x * 256 + threadIdx.x;
    if (i >= n4) return;
    float4 v = ((const float4*)src)[i];
    bf16x4_t o;
    o.x = (bf16_t)v.x; o.y = (bf16_t)v.y; o.z = (bf16_t)v.z; o.w = (bf16_t)v.w;
    ((bf16x4_t*)dst)[i] = o;
}

// dst[cols][rows] (bf16) = src[rows][cols]^T (fp32), 64x64 LDS tiles (+1 pad col).
__global__ __launch_bounds__(256) void transpose_convert(
    const float* __restrict__ src, bf16_t* __restrict__ dst,
    int rows, int cols)
{
    __shared__ bf16_t t[64][65];
    const int tx = threadIdx.x & 63;
    const int ty = threadIdx.x >> 6;
    const int c0 = blockIdx.x * 64;
    const int r0 = blockIdx.y * 64;
#pragma unroll
    for (int r = ty; r < 64; r += 4)
        t[r][tx] = (bf16_t)src[(size_t)(r0 + r) * cols + c0 + tx];
    __syncthreads();
#pragma unroll
    for (int r = ty; r < 64; r += 4)
        dst[(size_t)(c0 + r) * rows + r0 + tx] = t[tx][r];
}

__global__ void concat_bias(const float* __restrict__ bq, const float* __restrict__ bk,
                            const float* __restrict__ bv, float* __restrict__ o) {
    int i = blockIdx.x * 256 + threadIdx.x;
    if (i >= 3072) return;
    o[i] = (i < 2048) ? bq[i] : (i < 2560 ? bk[i - 2048] : bv[i - 2560]);
}

// Per-token grouped attention (softmax over G=4 groups at same position), bf16 in/out.
// One block/token; wave w -> heads 4w..4w+3; lane holds elems 2*lane, 2*lane+1.
// Writes DIRECTLY to the compact [16384][2048] buffer (so=2048) -> no compact_q pass.
__global__ __launch_bounds__(256) void gqa_attn(
    const bf16_t* __restrict__ q, int sq,
    const bf16_t* __restrict__ kv, int skv,
    bf16_t* __restrict__ out, int so)
{
    const int token = blockIdx.x;
    const int wave = threadIdx.x >> 6, lane = threadIdx.x & 63;
    const bf16_t* qb  = q  + (size_t)token * sq;
    const bf16_t* kvb = kv + (size_t)token * skv;
    const float scale = 0.08838834764831845f;  // 1/sqrt(128)
    float k0[4], k1[4], v0[4], v1[4];
#pragma unroll
    for (int g = 0; g < 4; ++g) {
        uint32_t ku = *(const uint32_t*)(kvb + g * 128 + lane * 2);
        k0[g] = __uint_as_float(ku << 16);
        k1[g] = __uint_as_float(ku & 0xffff0000u);
        uint32_t vu = *(const uint32_t*)(kvb + 512 + g * 128 + lane * 2);
        v0[g] = __uint_as_float(vu << 16);
        v1[g] = __uint_as_float(vu & 0xffff0000u);
    }
#pragma unroll
    for (int hh = 0; hh < 4; ++hh) {
        const int h = wave * 4 + hh;
        uint32_t qu = *(const uint32_t*)(qb + h * 128 + lane * 2);
        float q0 = __uint_as_float(qu << 16);
        float q1 = __uint_as_float(qu & 0xffff0000u);
        float s[4];
#pragma unroll
        for (int g = 0; g < 4; ++g) s[g] = q0 * k0[g] + q1 * k1[g];
#pragma unroll
        for (int off = 32; off > 0; off >>= 1)
#pragma unroll
            for (int g = 0; g < 4; ++g) s[g] += __shfl_xor(s[g], off);
        float mx = fmaxf(fmaxf(s[0], s[1]), fmaxf(s[2], s[3]));
        float e[4], sum = 0.f;
#pragma unroll
        for (int g = 0; g < 4; ++g) { e[g] = __expf((s[g] - mx) * scale); sum += e[g]; }
        const float rs = 1.0f / sum;
        float o0 = 0.f, o1 = 0.f;
#pragma unroll
        for (int g = 0; g < 4; ++g) { o0 += e[g] * v0[g]; o1 += e[g] * v1[g]; }
        o0 *= rs; o1 *= rs;
        bf16_t* op = out + (size_t)token * so + h * 128 + lane * 2;
        op[0] = (bf16_t)o0;
        op[1] = (bf16_t)o1;
    }
}

extern "C" void kernel_launch(void* const* d_in, const int* in_sizes, int n_in,
                              void* d_out, int out_size, void* d_ws, size_t ws_size,
                              hipStream_t stream) {
    const float* hs = (const float*)d_in[0];
    const float* Wq = (const float*)d_in[1];
    const float* bq = (const float*)d_in[2];
    const float* Wk = (const float*)d_in[3];
    const float* bk = (const float*)d_in[4];
    const float* Wv = (const float*)d_in[5];
    const float* bv = (const float*)d_in[6];
    const float* Wo = (const float*)d_in[7];
    const float* bo = (const float*)d_in[8];
    float* outp = (float*)d_out;
    char* ws = (char*)d_ws;

    // ws layout (88.1 MB total):
    //   Wt   [3072][2048] bf16 : 0          .. 12,582,912
    //   Wot  [2048][2048] bf16 : 12,582,912 .. 20,971,520
    //   bqkv [3072]       f32  : 20,971,520 .. 20,983,808
    //   X    (67,108,864 B)    : 20,983,808 .. 88,092,672   (hs_bf16, then atto)
    bf16_t* Wt     = (bf16_t*)(ws);
    bf16_t* Wot    = (bf16_t*)(ws + 12582912);
    float*  bqkv   = (float*)(ws + 20971520);
    bf16_t* hs_b   = (bf16_t*)(ws + 20983808);
    bf16_t* atto   = (bf16_t*)(ws + 20983808);  // overlays hs_b (dead after QKV gemm)
    // qkv bf16 [16384][3072] = 100.7 MB lives in d_out (134.2 MB fp32) as scratch.
    bf16_t* qkv    = (bf16_t*)d_out;

    // Convert + transpose weights, concat biases, convert activations.
    f32_to_bf16<<<32768, 256, 0, stream>>>(hs, hs_b, 8388608);          // 16384*2048/4
    transpose_convert<<<dim3(32, 32), 256, 0, stream>>>(Wq, Wt, 2048, 2048);
    transpose_convert<<<dim3(8, 32), 256, 0, stream>>>(Wk, Wt + (size_t)2048 * 2048, 2048, 512);
    transpose_convert<<<dim3(8, 32), 256, 0, stream>>>(Wv, Wt + (size_t)2560 * 2048, 2048, 512);
    transpose_convert<<<dim3(32, 32), 256, 0, stream>>>(Wo, Wot, 2048, 2048);
    concat_bias<<<12, 256, 0, stream>>>(bq, bk, bv, bqkv);

    // QKV projection: [16384,2048] x [2048,3072] -> qkv (bf16, in d_out scratch)
    // grid = 64 Mtiles * 12 Ntiles = 768 (%8==0 -> simple XCD swizzle valid)
    gemm256<bf16_t><<<768, 512, 0, stream>>>(hs_b, 2048, Wt, 2048, bqkv, qkv, 3072, 2048, 12);
    // Grouped attention: read q/kv from qkv, write compact [16384][2048] to atto.
    gqa_attn<<<16384, 256, 0, stream>>>(qkv, 3072, qkv + 2048, 3072, atto, 2048);
    // Output projection -> fp32 d_out ; grid = 64 * 8 = 512 (%8==0)
    gemm256<float><<<512, 512, 0, stream>>>(atto, 2048, Wot, 2048, bo, outp, 2048, 2048, 8);
}

// Round 3
// 632.758 us; speedup vs baseline: 1.1904x; 1.0745x over previous
//
#include <hip/hip_runtime.h>
#include <hip/hip_bf16.h>
#include <stdint.h>

typedef __bf16 bf16_t;
typedef __bf16 bf16x8 __attribute__((ext_vector_type(8)));
typedef __bf16 bf16x4_t __attribute__((ext_vector_type(4)));
typedef float f32x4 __attribute__((ext_vector_type(4)));

#define AS1 __attribute__((address_space(1)))
#define AS3 __attribute__((address_space(3)))

__device__ __forceinline__ void stage16(const bf16_t* g, char* l) {
    __builtin_amdgcn_global_load_lds((const AS1 uint32_t*)g, (AS3 uint32_t*)l, 16, 0, 0);
}

#define BAR()   __builtin_amdgcn_s_barrier()
#define LGKM0() asm volatile("s_waitcnt lgkmcnt(0)" ::: "memory")
#define VMC(N)  asm volatile("s_waitcnt vmcnt(" #N ")" ::: "memory")
#define PRIO(p) __builtin_amdgcn_s_setprio(p)

// ----------------------------------------------------------------------------
// 256x256 8-phase bf16 GEMM: C = A * Bt^T + bias.
// 512 threads = 8 waves (2M x 4N); per-wave output 128x64; 2 LDS buffers of
// BK=64 (128 KB total); st_16x32 swizzle via pre-swizzled global source +
// XOR'd ds_read (rule #21).
// Quadrant phase scheme (m201): per K-tile, phase q0 reads ALL 8 B-frags
// (held in regs, 32 VGPR) + 4 A-frags; phases q1..q3 read only 4 A-frags each
// -> per-phase reads 12/4/4/4 instead of 10/2 (less lgkm drain before MFMA).
// Stage windows (reads-complete -> earliest overwrite):
//   buf0-B done P1 -> stage >=P2 ; buf0-A done P4 -> stage >=P5
//   buf1-B done P5 -> stage >=P6 ; buf1-A done P8 -> stage next-iter P1
// Assignment: P1/P2 buf1-A(this, deferred), P3/P4 buf0-B(next),
//             P5/P6 buf0-A(next),           P7/P8 buf1-B(next).
// Counted waits: vmcnt(4) at P4 (retires prev-P7/P8 + this-P1/P2 = exactly
// what P5 reads) and at P8 (retires P3..P6 = what next-P1 reads); 2 stages
// (4 loads) stay in flight across every boundary. Epilogue iter: vmcnt(0) @P4.
// ----------------------------------------------------------------------------
template <typename OutT>
__global__ __launch_bounds__(512, 2) void gemm256(
    const bf16_t* __restrict__ A, int lda,
    const bf16_t* __restrict__ Bt, int ldb,
    const float* __restrict__ bias,
    OutT* __restrict__ C, int ldc,
    int K, int nTilesN)
{
    __shared__ char smem[131072];
    const int tid  = threadIdx.x;
    const int wave = tid >> 6;
    const int lane = tid & 63;
    const int wm = wave >> 2;   // 0..1 -> rows wm*128..+128
    const int wn = wave & 3;    // 0..3 -> cols wn*64..+64

    // XCD-aware bijective swizzle (gridDim.x % 8 == 0 guaranteed by caller)
    const int bid = blockIdx.x;
    const int swz = (bid & 7) * ((int)gridDim.x >> 3) + (bid >> 3);
    const int m0 = (swz / nTilesN) << 8;
    const int n0 = (swz % nTilesN) << 8;

    // Staging source: wave w, inst j covers subtile rg=w*2+j; lane's 16B chunk
    // col = (lane&3)*8, XOR 16 when subtile row (lane>>2) bit 3 set (inverse
    // st_16x32 pre-swizzle on the global source address).
    const int srow = lane >> 2;
    const int scol = ((lane & 3) * 8) ^ ((lane & 32) >> 1);
    const bf16_t* aS0 = A  + (size_t)(m0 + wave * 32 + srow) * lda + scol;
    const bf16_t* aS1 = aS0 + (size_t)16 * lda;
    const bf16_t* bS0 = Bt + (size_t)(n0 + wave * 32 + srow) * ldb + scol;
    const bf16_t* bS1 = bS0 + (size_t)16 * ldb;

    // LDS map: A(b,kk) = b*65536 + kk*16384 ; B(b,kk) = +32768.
#define STAGE_A(b,kk,kb) do { \
    stage16(aS0 + (kb) + (kk)*32, smem + (b)*65536 + (kk)*16384 + wave*2048); \
    stage16(aS1 + (kb) + (kk)*32, smem + (b)*65536 + (kk)*16384 + wave*2048 + 1024); } while(0)
#define STAGE_B(b,kk,kb) do { \
    stage16(bS0 + (kb) + (kk)*32, smem + (b)*65536 + 32768 + (kk)*16384 + wave*2048); \
    stage16(bS1 + (kb) + (kk)*32, smem + (b)*65536 + 32768 + (kk)*16384 + wave*2048 + 1024); } while(0)

    // ds_read: lane l -> row l&15, k-chunk (l>>4)*16B, with st_16x32 XOR.
    const int rdLane = (lane & 15) * 64 + (((lane >> 4) * 16) ^ ((lane & 8) << 2));
    const char* aRdB = smem + rdLane + wm * 8192;           // + mi*1024 + A(b,kk)
    const char* bRdB = smem + 32768 + rdLane + wn * 4096;   // + ni*1024 + base(b,kk)

    f32x4 acc[8][4];
#pragma unroll
    for (int i = 0; i < 8; ++i)
#pragma unroll
        for (int j = 0; j < 4; ++j) acc[i][j] = (f32x4){0.f, 0.f, 0.f, 0.f};
    bf16x8 bfr[2][4];   // [kk][ni], held across the K-tile's 4 phases
    bf16x8 af[2][2];    // [t][kk], current mi-pair

#define RDB8(b) { _Pragma("unroll") \
    for (int kk = 0; kk < 2; ++kk) _Pragma("unroll") \
        for (int ni = 0; ni < 4; ++ni) \
            bfr[kk][ni] = *(const bf16x8*)(bRdB + (b)*65536 + kk*16384 + ni*1024); }
#define RDA(b,mp) { _Pragma("unroll") \
    for (int t = 0; t < 2; ++t) _Pragma("unroll") \
        for (int kk = 0; kk < 2; ++kk) \
            af[t][kk] = *(const bf16x8*)(aRdB + (b)*65536 + kk*16384 + ((mp)*2+t)*1024); }
#define MF(mp) { _Pragma("unroll") \
    for (int t = 0; t < 2; ++t) _Pragma("unroll") \
        for (int ni = 0; ni < 4; ++ni) _Pragma("unroll") \
            for (int kk = 0; kk < 2; ++kk) \
                acc[(mp)*2+t][ni] = __builtin_amdgcn_mfma_f32_16x16x32_bf16(af[t][kk], bfr[kk][ni], acc[(mp)*2+t][ni], 0, 0, 0); }
#define PHASE(RDS, STG, MFM, WAIT) do { \
    RDS; STG; BAR(); LGKM0(); PRIO(1); MFM; PRIO(0); WAIT; BAR(); } while(0)

    // Prologue: buf0 A+B @k=0 (4 stages), buf1-B @k=64 (2 stages).
    // VMC(4) retires buf0's 4 stages, leaves buf1-B's 2 in flight (steady state).
    STAGE_A(0, 0, 0);  STAGE_A(0, 1, 0);  STAGE_B(0, 0, 0);  STAGE_B(0, 1, 0);
    STAGE_B(1, 0, 64); STAGE_B(1, 1, 64);
    VMC(4);
    BAR();

    const int NI = K >> 7;
    for (int it = 0; it < NI - 1; ++it) {
        const int kB  = (it << 7) + 64;    // this iter's buf1 (A deferred)
        const int kN0 = (it << 7) + 128;   // next buf0
        const int kN1 = (it << 7) + 192;   // next buf1
        PHASE(RDB8(0); RDA(0,0), STAGE_A(1,0,kB),  MF(0), );
        PHASE(RDA(0,1),          STAGE_A(1,1,kB),  MF(1), );
        PHASE(RDA(0,2),          STAGE_B(0,0,kN0), MF(2), );
        PHASE(RDA(0,3),          STAGE_B(0,1,kN0), MF(3), VMC(4));
        PHASE(RDB8(1); RDA(1,0), STAGE_A(0,0,kN0), MF(0), );
        PHASE(RDA(1,1),          STAGE_A(0,1,kN0), MF(1), );
        PHASE(RDA(1,2),          STAGE_B(1,0,kN1), MF(2), );
        PHASE(RDA(1,3),          STAGE_B(1,1,kN1), MF(3), VMC(4));
    }
    // Epilogue iteration: buf1-A still needs staging at P1/P2; no next-tile stages.
    {
        const int kB = ((NI - 1) << 7) + 64;
        PHASE(RDB8(0); RDA(0,0), STAGE_A(1,0,kB), MF(0), );
        PHASE(RDA(0,1),          STAGE_A(1,1,kB), MF(1), );
        PHASE(RDA(0,2),          ,                MF(2), );
        PHASE(RDA(0,3),          ,                MF(3), VMC(0));
        PHASE(RDB8(1); RDA(1,0), ,                MF(0), );
        PHASE(RDA(1,1),          ,                MF(1), );
        PHASE(RDA(1,2),          ,                MF(2), );
        RDA(1,3); BAR(); LGKM0(); PRIO(1); MF(3); PRIO(0);
    }
    BAR();

    // ---- Epilogue: LDS-staged coalesced C write (two 128-row halves) ----
    // Write-in swizzle: colb ^= quad*16*CSZ (spreads the 4 quads across bank
    // groups; bijective within the 256-col row). Readback applies same XOR.
    {
        const int mrow = lane & 15;
        const int quad = lane >> 4;
        constexpr int CSZ = (int)sizeof(OutT);
        float bias_v[4];
#pragma unroll
        for (int ni = 0; ni < 4; ++ni)
            bias_v[ni] = bias[n0 + wn * 64 + ni * 16 + mrow];
#pragma unroll
        for (int h = 0; h < 2; ++h) {
            if (wm == h) {
#pragma unroll
                for (int ni = 0; ni < 4; ++ni) {
                    const int colb = (wn * 64 + ni * 16 + mrow) * CSZ;
#pragma unroll
                    for (int mi = 0; mi < 8; ++mi)
#pragma unroll
                        for (int r = 0; r < 4; ++r) {
                            const int lrow = mi * 16 + quad * 4 + r;
                            *(OutT*)(smem + lrow * 256 * CSZ + (colb ^ (quad * 16 * CSZ))) =
                                (OutT)(acc[mi][ni][r] + bias_v[ni]);
                        }
                }
            }
            BAR();
            const int ROUNDS = 128 * 256 * CSZ / 8192;
#pragma unroll
            for (int rd = 0; rd < ROUNDS; ++rd) {
                const int flat = rd * 8192 + tid * 16;
                const int lrow = flat / (256 * CSZ);
                const int colb = flat % (256 * CSZ);
                const int q2 = (lrow >> 2) & 3;
                uint4 v = *(const uint4*)(smem + lrow * 256 * CSZ + (colb ^ (q2 * 16 * CSZ)));
                *(uint4*)((char*)C + ((size_t)(m0 + h * 128 + lrow) * ldc + n0) * CSZ + colb) = v;
            }
            BAR();
        }
    }
#undef STAGE_A
#undef STAGE_B
#undef RDB8
#undef RDA
#undef MF
#undef PHASE
}

// fp32 -> bf16 elementwise, 4 elems/thread.
__global__ __launch_bounds__(256) void f32_to_bf16(const float* __restrict__ src,
                                                   bf16_t* __restrict__ dst, int n4) {
    int i = blockIdx.x * 256 + threadIdx.x;
    if (i >= n4) return;
    float4 v = ((const float4*)src)[i];
    bf16x4_t o;
    o.x = (bf16_t)v.x; o.y = (bf16_t)v.y; o.z = (bf16_t)v.z; o.w = (bf16_t)v.w;
    ((bf16x4_t*)dst)[i] = o;
}

// dst[cols][rows] (bf16) = src[rows][cols]^T (fp32), 64x64 LDS tiles (+1 pad col).
__global__ __launch_bounds__(256) void transpose_convert(
    const float* __restrict__ src, bf16_t* __restrict__ dst,
    int rows, int cols)
{
    __shared__ bf16_t t[64][65];
    const int tx = threadIdx.x & 63;
    const int ty = threadIdx.x >> 6;
    const int c0 = blockIdx.x * 64;
    const int r0 = blockIdx.y * 64;
#pragma unroll
    for (int r = ty; r < 64; r += 4)
        t[r][tx] = (bf16_t)src[(size_t)(r0 + r) * cols + c0 + tx];
    __syncthreads();
#pragma unroll
    for (int r = ty; r < 64; r += 4)
        dst[(size_t)(c0 + r) * rows + r0 + tx] = t[tx][r];
}

__global__ void concat_bias(const float* __restrict__ bq, const float* __restrict__ bk,
                            const float* __restrict__ bv, float* __restrict__ o) {
    int i = blockIdx.x * 256 + threadIdx.x;
    if (i >= 3072) return;
    o[i] = (i < 2048) ? bq[i] : (i < 2560 ? bk[i - 2048] : bv[i - 2560]);
}

// Per-token grouped attention (softmax over G=4 groups at same position), bf16 in/out.
// One block/token; wave w -> heads 4w..4w+3; lane holds elems 2*lane, 2*lane+1.
// Writes DIRECTLY to the compact [16384][2048] buffer (so=2048).
__global__ __launch_bounds__(256) void gqa_attn(
    const bf16_t* __restrict__ q, int sq,
    const bf16_t* __restrict__ kv, int skv,
    bf16_t* __restrict__ out, int so)
{
    const int token = blockIdx.x;
    const int wave = threadIdx.x >> 6, lane = threadIdx.x & 63;
    const bf16_t* qb  = q  + (size_t)token * sq;
    const bf16_t* kvb = kv + (size_t)token * skv;
    const float scale = 0.08838834764831845f;  // 1/sqrt(128)
    float k0[4], k1[4], v0[4], v1[4];
#pragma unroll
    for (int g = 0; g < 4; ++g) {
        uint32_t ku = *(const uint32_t*)(kvb + g * 128 + lane * 2);
        k0[g] = __uint_as_float(ku << 16);
        k1[g] = __uint_as_float(ku & 0xffff0000u);
        uint32_t vu = *(const uint32_t*)(kvb + 512 + g * 128 + lane * 2);
        v0[g] = __uint_as_float(vu << 16);
        v1[g] = __uint_as_float(vu & 0xffff0000u);
    }
#pragma unroll
    for (int hh = 0; hh < 4; ++hh) {
        const int h = wave * 4 + hh;
        uint32_t qu = *(const uint32_t*)(qb + h * 128 + lane * 2);
        float q0 = __uint_as_float(qu << 16);
        float q1 = __uint_as_float(qu & 0xffff0000u);
        float s[4];
#pragma unroll
        for (int g = 0; g < 4; ++g) s[g] = q0 * k0[g] + q1 * k1[g];
#pragma unroll
        for (int off = 32; off > 0; off >>= 1)
#pragma unroll
            for (int g = 0; g < 4; ++g) s[g] += __shfl_xor(s[g], off);
        float mx = fmaxf(fmaxf(s[0], s[1]), fmaxf(s[2], s[3]));
        float e[4], sum = 0.f;
#pragma unroll
        for (int g = 0; g < 4; ++g) { e[g] = __expf((s[g] - mx) * scale); sum += e[g]; }
        const float rs = 1.0f / sum;
        float o0 = 0.f, o1 = 0.f;
#pragma unroll
        for (int g = 0; g < 4; ++g) { o0 += e[g] * v0[g]; o1 += e[g] * v1[g]; }
        o0 *= rs; o1 *= rs;
        bf16_t* op = out + (size_t)token * so + h * 128 + lane * 2;
        op[0] = (bf16_t)o0;
        op[1] = (bf16_t)o1;
    }
}

extern "C" void kernel_launch(void* const* d_in, const int* in_sizes, int n_in,
                              void* d_out, int out_size, void* d_ws, size_t ws_size,
                              hipStream_t stream) {
    const float* hs = (const float*)d_in[0];
    const float* Wq = (const float*)d_in[1];
    const float* bq = (const float*)d_in[2];
    const float* Wk = (const float*)d_in[3];
    const float* bk = (const float*)d_in[4];
    const float* Wv = (const float*)d_in[5];
    const float* bv = (const float*)d_in[6];
    const float* Wo = (const float*)d_in[7];
    const float* bo = (const float*)d_in[8];
    float* outp = (float*)d_out;
    char* ws = (char*)d_ws;

    // ws layout (88.1 MB total):
    //   Wt   [3072][2048] bf16 : 0          .. 12,582,912
    //   Wot  [2048][2048] bf16 : 12,582,912 .. 20,971,520
    //   bqkv [3072]       f32  : 20,971,520 .. 20,983,808
    //   X    (67,108,864 B)    : 20,983,808 .. 88,092,672   (hs_bf16, then atto)
    bf16_t* Wt     = (bf16_t*)(ws);
    bf16_t* Wot    = (bf16_t*)(ws + 12582912);
    float*  bqkv   = (float*)(ws + 20971520);
    bf16_t* hs_b   = (bf16_t*)(ws + 20983808);
    bf16_t* atto   = (bf16_t*)(ws + 20983808);  // overlays hs_b (dead after QKV gemm)
    // qkv bf16 [16384][3072] = 100.7 MB lives in d_out (134.2 MB fp32) as scratch.
    bf16_t* qkv    = (bf16_t*)d_out;

    // Convert + transpose weights, concat biases, convert activations.
    f32_to_bf16<<<32768, 256, 0, stream>>>(hs, hs_b, 8388608);          // 16384*2048/4
    transpose_convert<<<dim3(32, 32), 256, 0, stream>>>(Wq, Wt, 2048, 2048);
    transpose_convert<<<dim3(8, 32), 256, 0, stream>>>(Wk, Wt + (size_t)2048 * 2048, 2048, 512);
    transpose_convert<<<dim3(8, 32), 256, 0, stream>>>(Wv, Wt + (size_t)2560 * 2048, 2048, 512);
    transpose_convert<<<dim3(32, 32), 256, 0, stream>>>(Wo, Wot, 2048, 2048);
    concat_bias<<<12, 256, 0, stream>>>(bq, bk, bv, bqkv);

    // QKV projection: [16384,2048] x [2048,3072] -> qkv (bf16, in d_out scratch)
    // grid = 64 Mtiles * 12 Ntiles = 768 (%8==0 -> simple XCD swizzle valid)
    gemm256<bf16_t><<<768, 512, 0, stream>>>(hs_b, 2048, Wt, 2048, bqkv, qkv, 3072, 2048, 12);
    // Grouped attention: read q/kv from qkv, write compact [16384][2048] to atto.
    gqa_attn<<<16384, 256, 0, stream>>>(qkv, 3072, qkv + 2048, 3072, atto, 2048);
    // Output projection -> fp32 d_out ; grid = 64 * 8 = 512 (%8==0)
    gemm256<float><<<512, 512, 0, stream>>>(atto, 2048, Wot, 2048, bo, outp, 2048, 2048, 8);
}